// Round 5
// baseline (103.317 us; speedup 1.0000x reference)
//
#include <hip/hip_runtime.h>
#include <math.h>

#define EPS 1e-8f

// 2-wide float vector: component .x / .y = two independent batch elements.
// Structural ILP-2 + CDNA packed-fp32 (v_pk_fma_f32) from <2 x float> IR.
typedef float v2  __attribute__((ext_vector_type(2)));
typedef float f4a __attribute__((ext_vector_type(4), aligned(4)));  // 4B-aligned vec loads

static __device__ __forceinline__ v2 vfma(v2 a, v2 b, v2 c) {
#if __has_builtin(__builtin_elementwise_fma)
    return __builtin_elementwise_fma(a, b, c);
#else
    return a * b + c;   // hipcc default fp-contract=fast
#endif
}
static __device__ __forceinline__ v2 vrsq(v2 x) {
    v2 r; r.x = __builtin_amdgcn_rsqf(x.x); r.y = __builtin_amdgcn_rsqf(x.y); return r;
}
static __device__ __forceinline__ v2 vsq(v2 x)         { return __builtin_elementwise_sqrt(x); }
static __device__ __forceinline__ v2 vab(v2 x)         { return __builtin_elementwise_abs(x); }
static __device__ __forceinline__ v2 vmx(v2 a, v2 b)   { return __builtin_elementwise_max(a, b); }
static __device__ __forceinline__ v2 vcs(v2 a, v2 b)   { return __builtin_elementwise_copysign(a, b); }

// Jacobi angle: 1 rsq, then TWO PARALLEL sqrts (short critical path).
//   r = sqrt(h^2+4apq^2); cos2t = |h|/r; c = sqrt((1+cos2t)/2);
//   s = sign(apq*h)*sqrt((1-cos2t)/2); t*apq = sign(h)*(r-|h|)/2.
// sign(apq*h): IEEE underflow keeps the XOR'd sign, so copysign is exact.
// |h|+1e-18 => rad >= 1e-36 (normal): h=apq=0 gives identity rotation.
static __device__ __forceinline__ void jangle(v2 app, v2 aqq, v2 apq,
                                              v2 &c, v2 &s, v2 &app2, v2 &aqq2) {
    v2 h   = aqq - app;
    v2 ah  = vab(h) + 1e-18f;
    v2 v   = apq + apq;
    v2 rad = vfma(ah, ah, v * v);
    v2 rr  = vrsq(rad);
    v2 c2  = ah * rr;                                  // cos(2theta) in [0,1]
    c = vsq(vfma((v2)0.5f, c2, (v2)0.5f));
    v2 s2 = vmx(vfma((v2)(-0.5f), c2, (v2)0.5f), (v2)0.0f);
    s = vcs(vsq(s2), apq * h);
    v2 dl = vcs(vfma(rad, rr, -ah), h) * 0.5f;         // t*apq, signed; rad*rr-ah >= 0
    app2 = app - dl;
    aqq2 = aqq + dl;
}

// 3-sweep cyclic Jacobi on symmetric (a00..a22); Q = eigenvectors, diag -> eigvals.
// Sweep 1 specialized for Q == identity.
static __device__ __forceinline__ void eigh3(
    v2 &a00, v2 &a01, v2 &a02, v2 &a11, v2 &a12, v2 &a22,
    v2 &q00, v2 &q01, v2 &q02, v2 &q10, v2 &q11, v2 &q12, v2 &q20, v2 &q21, v2 &q22)
{
    v2 c, s, x, y, t0, t1;
    // sweep 1 (Q specialized)
    jangle(a00, a11, a01, c, s, x, y); a00 = x; a11 = y; a01 = (v2)0.0f;
    t0 = a02; t1 = a12; a02 = vfma(c, t0, -s * t1); a12 = vfma(c, t1, s * t0);
    q00 = c; q01 = s; q10 = -s; q11 = c;

    jangle(a00, a22, a02, c, s, x, y); a00 = x; a22 = y; a02 = (v2)0.0f;
    t0 = a01; t1 = a12; a01 = vfma(c, t0, -s * t1); a12 = vfma(c, t1, s * t0);
    q02 = s * q00; q12 = s * q10; q20 = -s; q22 = c;
    q00 = c * q00; q10 = c * q10;

    jangle(a11, a22, a12, c, s, x, y); a11 = x; a22 = y; a12 = (v2)0.0f;
    t0 = a01; t1 = a02; a01 = vfma(c, t0, -s * t1); a02 = vfma(c, t1, s * t0);
    t0 = q01; t1 = q02; q01 = vfma(c, t0, -s * t1); q02 = vfma(s, t0, c * t1);
    t0 = q11; t1 = q12; q11 = vfma(c, t0, -s * t1); q12 = vfma(s, t0, c * t1);
    q21 = -s * q22; q22 = c * q22;

    // sweeps 2..3 (generic)
    #pragma unroll
    for (int sw = 0; sw < 2; ++sw) {
        jangle(a00, a11, a01, c, s, x, y); a00 = x; a11 = y; a01 = (v2)0.0f;
        t0 = a02; t1 = a12; a02 = vfma(c, t0, -s * t1); a12 = vfma(c, t1, s * t0);
        t0 = q00; t1 = q01; q00 = vfma(c, t0, -s * t1); q01 = vfma(s, t0, c * t1);
        t0 = q10; t1 = q11; q10 = vfma(c, t0, -s * t1); q11 = vfma(s, t0, c * t1);
        t0 = q20; t1 = q21; q20 = vfma(c, t0, -s * t1); q21 = vfma(s, t0, c * t1);

        jangle(a00, a22, a02, c, s, x, y); a00 = x; a22 = y; a02 = (v2)0.0f;
        t0 = a01; t1 = a12; a01 = vfma(c, t0, -s * t1); a12 = vfma(c, t1, s * t0);
        t0 = q00; t1 = q02; q00 = vfma(c, t0, -s * t1); q02 = vfma(s, t0, c * t1);
        t0 = q10; t1 = q12; q10 = vfma(c, t0, -s * t1); q12 = vfma(s, t0, c * t1);
        t0 = q20; t1 = q22; q20 = vfma(c, t0, -s * t1); q22 = vfma(s, t0, c * t1);

        jangle(a11, a22, a12, c, s, x, y); a11 = x; a22 = y; a12 = (v2)0.0f;
        t0 = a01; t1 = a02; a01 = vfma(c, t0, -s * t1); a02 = vfma(c, t1, s * t0);
        t0 = q01; t1 = q02; q01 = vfma(c, t0, -s * t1); q02 = vfma(s, t0, c * t1);
        t0 = q11; t1 = q12; q11 = vfma(c, t0, -s * t1); q12 = vfma(s, t0, c * t1);
        t0 = q21; t1 = q22; q21 = vfma(c, t0, -s * t1); q22 = vfma(s, t0, c * t1);
    }
}

__global__ __launch_bounds__(256, 4) void wasserstein_log_kernel(
    const float* __restrict__ miu1, const float* __restrict__ miu2,
    const float* __restrict__ cov1, const float* __restrict__ cov2,
    float* __restrict__ out, int B)
{
    int b0 = blockIdx.x * blockDim.x + threadIdx.x;
    int nT = (B + 1) >> 1;
    if (b0 >= nT) return;
    bool pair = (2 * b0 + 1 < B);   // wave-uniform true for even B

    v2 k00, k01, k02, k11, k12, k22;
    v2 m00, m01, m02, m11, m12, m22;
    v2 u0, u1, u2;  // miu2 - miu1, per pair

    if (pair) {
        size_t cb = 18 * (size_t)b0;
        const f4a* p1 = (const f4a*)(cov1 + cb);
        f4a A0 = p1[0], A1 = p1[1], A2 = p1[2], A3 = p1[3];
        float a17 = cov1[cb + 17];
        k00.x = A0.x; k00.y = A2.y;   // f0,  f9
        k01.x = A0.y; k01.y = A2.z;   // f1,  f10
        k02.x = A0.z; k02.y = A2.w;   // f2,  f11
        k11.x = A1.x; k11.y = A3.y;   // f4,  f13
        k12.x = A1.y; k12.y = A3.z;   // f5,  f14
        k22.x = A2.x; k22.y = a17;    // f8,  f17

        const f4a* p2 = (const f4a*)(cov2 + cb);
        f4a B0 = p2[0], B1 = p2[1], B2 = p2[2], B3 = p2[3];
        float b17 = cov2[cb + 17];
        m00.x = B0.x; m00.y = B2.y;
        m01.x = B0.y; m01.y = B2.z;
        m02.x = B0.z; m02.y = B2.w;
        m11.x = B1.x; m11.y = B3.y;
        m12.x = B1.y; m12.y = B3.z;
        m22.x = B2.x; m22.y = b17;

        size_t mb = 6 * (size_t)b0;
        const f4a* q1 = (const f4a*)(miu1 + mb);
        const f4a* q2 = (const f4a*)(miu2 + mb);
        f4a M1 = q1[0]; float m1a = miu1[mb + 4], m1b = miu1[mb + 5];
        f4a M2 = q2[0]; float m2a = miu2[mb + 4], m2b = miu2[mb + 5];
        u0.x = M2.x - M1.x; u0.y = M2.w - M1.w;
        u1.x = M2.y - M1.y; u1.y = m2a - m1a;
        u2.x = M2.z - M1.z; u2.y = m2b - m1b;
    } else {
        // tail (odd B): single element duplicated into both lanes
        size_t cb = 9 * (size_t)(B - 1);
        k00 = (v2)cov1[cb+0]; k01 = (v2)cov1[cb+1]; k02 = (v2)cov1[cb+2];
        k11 = (v2)cov1[cb+4]; k12 = (v2)cov1[cb+5]; k22 = (v2)cov1[cb+8];
        m00 = (v2)cov2[cb+0]; m01 = (v2)cov2[cb+1]; m02 = (v2)cov2[cb+2];
        m11 = (v2)cov2[cb+4]; m12 = (v2)cov2[cb+5]; m22 = (v2)cov2[cb+8];
        size_t mb = 3 * (size_t)(B - 1);
        u0 = (v2)(miu2[mb+0] - miu1[mb+0]);
        u1 = (v2)(miu2[mb+1] - miu1[mb+1]);
        u2 = (v2)(miu2[mb+2] - miu1[mb+2]);
    }

    // ---- eigh(cov1 + eps I) ----
    v2 a00 = k00 + EPS, a01 = k01, a02 = k02,
       a11 = k11 + EPS, a12 = k12, a22 = k22 + EPS;
    v2 q00, q01, q02, q10, q11, q12, q20, q21, q22;
    eigh3(a00, a01, a02, a11, a12, a22,
          q00, q01, q02, q10, q11, q12, q20, q21, q22);

    v2 w0 = vmx(vab(a00), (v2)1e-12f);
    v2 w1 = vmx(vab(a11), (v2)1e-12f);
    v2 w2 = vmx(vab(a22), (v2)1e-12f);
    v2 di0 = vrsq(w0), di1 = vrsq(w1), di2 = vrsq(w2);
    v2 d0 = w0 * di0, d1 = w1 * di1, d2 = w2 * di2;     // sqrt(w)

    // ---- T = M Q ; G = Q^T T (symmetric) ----
    v2 T00 = vfma(m00, q00, vfma(m01, q10, m02 * q20));
    v2 T01 = vfma(m00, q01, vfma(m01, q11, m02 * q21));
    v2 T02 = vfma(m00, q02, vfma(m01, q12, m02 * q22));
    v2 T10 = vfma(m01, q00, vfma(m11, q10, m12 * q20));
    v2 T11 = vfma(m01, q01, vfma(m11, q11, m12 * q21));
    v2 T12 = vfma(m01, q02, vfma(m11, q12, m12 * q22));
    v2 T20 = vfma(m02, q00, vfma(m12, q10, m22 * q20));
    v2 T21 = vfma(m02, q01, vfma(m12, q11, m22 * q21));
    v2 T22 = vfma(m02, q02, vfma(m12, q12, m22 * q22));

    v2 g00 = vfma(q00, T00, vfma(q10, T10, q20 * T20));
    v2 g01 = vfma(q00, T01, vfma(q10, T11, q20 * T21));
    v2 g02 = vfma(q00, T02, vfma(q10, T12, q20 * T22));
    v2 g11 = vfma(q01, T01, vfma(q11, T11, q21 * T21));
    v2 g12 = vfma(q01, T02, vfma(q11, T12, q21 * T22));
    v2 g22 = vfma(q02, T02, vfma(q12, T12, q22 * T22));

    // ---- C' = D G D + eps I ----
    v2 cp00 = vfma(w0, g00, (v2)EPS);
    v2 cp11 = vfma(w1, g11, (v2)EPS);
    v2 cp22 = vfma(w2, g22, (v2)EPS);
    v2 cp01 = d0 * d1 * g01;
    v2 cp02 = d0 * d2 * g02;
    v2 cp12 = d1 * d2 * g12;

    // ---- eigh(C') ----
    v2 e00, e01, e02, e10, e11, e12, e20, e21, e22;
    eigh3(cp00, cp01, cp02, cp11, cp12, cp22,
          e00, e01, e02, e10, e11, e12, e20, e21, e22);
    v2 v0 = vmx(vab(cp00), (v2)1e-12f);
    v2 v1 = vmx(vab(cp11), (v2)1e-12f);
    v2 v2v = vmx(vab(cp22), (v2)1e-12f);
    v2 ts0 = v0 * vrsq(v0);
    v2 ts1 = v1 * vrsq(v1);
    v2 ts2 = v2v * vrsq(v2v);

    // ---- U = Q D Qc, P = Q D^-1 Qc ----
    v2 Ed00 = d0*e00, Ed01 = d0*e01, Ed02 = d0*e02;
    v2 Ed10 = d1*e10, Ed11 = d1*e11, Ed12 = d1*e12;
    v2 Ed20 = d2*e20, Ed21 = d2*e21, Ed22 = d2*e22;
    v2 Ei00 = di0*e00, Ei01 = di0*e01, Ei02 = di0*e02;
    v2 Ei10 = di1*e10, Ei11 = di1*e11, Ei12 = di1*e12;
    v2 Ei20 = di2*e20, Ei21 = di2*e21, Ei22 = di2*e22;

    v2 U00 = vfma(q00, Ed00, vfma(q01, Ed10, q02 * Ed20));
    v2 U01 = vfma(q00, Ed01, vfma(q01, Ed11, q02 * Ed21));
    v2 U02 = vfma(q00, Ed02, vfma(q01, Ed12, q02 * Ed22));
    v2 U10 = vfma(q10, Ed00, vfma(q11, Ed10, q12 * Ed20));
    v2 U11 = vfma(q10, Ed01, vfma(q11, Ed11, q12 * Ed21));
    v2 U12 = vfma(q10, Ed02, vfma(q11, Ed12, q12 * Ed22));
    v2 U20 = vfma(q20, Ed00, vfma(q21, Ed10, q22 * Ed20));
    v2 U21 = vfma(q20, Ed01, vfma(q21, Ed11, q22 * Ed21));
    v2 U22 = vfma(q20, Ed02, vfma(q21, Ed12, q22 * Ed22));

    v2 P00 = vfma(q00, Ei00, vfma(q01, Ei10, q02 * Ei20));
    v2 P01 = vfma(q00, Ei01, vfma(q01, Ei11, q02 * Ei21));
    v2 P02 = vfma(q00, Ei02, vfma(q01, Ei12, q02 * Ei22));
    v2 P10 = vfma(q10, Ei00, vfma(q11, Ei10, q12 * Ei20));
    v2 P11 = vfma(q10, Ei01, vfma(q11, Ei11, q12 * Ei21));
    v2 P12 = vfma(q10, Ei02, vfma(q11, Ei12, q12 * Ei22));
    v2 P20 = vfma(q20, Ei00, vfma(q21, Ei10, q22 * Ei20));
    v2 P21 = vfma(q20, Ei01, vfma(q21, Ei11, q22 * Ei21));
    v2 P22 = vfma(q20, Ei02, vfma(q21, Ei12, q22 * Ei22));

    // ---- W = U diag(ts) P^T + P diag(ts) U^T (symmetric) ----
    v2 A0v = ts0 * U00, A1v = ts1 * U01, A2v = ts2 * U02;
    v2 B0v = ts0 * U10, B1v = ts1 * U11, B2v = ts2 * U12;
    v2 C0v = ts0 * U20, C1v = ts1 * U21, C2v = ts2 * U22;

    v2 W00 = 2.0f * vfma(A0v, P00, vfma(A1v, P01, A2v * P02));
    v2 W11 = 2.0f * vfma(B0v, P10, vfma(B1v, P11, B2v * P12));
    v2 W22 = 2.0f * vfma(C0v, P20, vfma(C1v, P21, C2v * P22));
    v2 W01 = vfma(A0v, P10, vfma(A1v, P11, vfma(A2v, P12,
             vfma(B0v, P00, vfma(B1v, P01, B2v * P02)))));
    v2 W02 = vfma(A0v, P20, vfma(A1v, P21, vfma(A2v, P22,
             vfma(C0v, P00, vfma(C1v, P01, C2v * P02)))));
    v2 W12 = vfma(B0v, P20, vfma(B1v, P21, vfma(B2v, P22,
             vfma(C0v, P10, vfma(C1v, P11, C2v * P12)))));

    // ---- cov_velocity = W - 2 cov1 ----
    v2 o00 = vfma((v2)(-2.0f), k00, W00);
    v2 o01 = vfma((v2)(-2.0f), k01, W01);
    v2 o02 = vfma((v2)(-2.0f), k02, W02);
    v2 o11 = vfma((v2)(-2.0f), k11, W11);
    v2 o12 = vfma((v2)(-2.0f), k12, W12);
    v2 o22 = vfma((v2)(-2.0f), k22, W22);

    // ---- stores ----
    int e0 = 2 * b0;
    float* om = out + 3 * (size_t)e0;
    om[0] = u0.x; om[1] = u1.x; om[2] = u2.x;
    float* oc = out + 3 * (size_t)B + 9 * (size_t)e0;
    f4a S0; S0.x = o00.x; S0.y = o01.x; S0.z = o02.x; S0.w = o01.x;
    f4a S1; S1.x = o11.x; S1.y = o12.x; S1.z = o02.x; S1.w = o12.x;
    ((f4a*)oc)[0] = S0; ((f4a*)oc)[1] = S1; oc[8] = o22.x;
    if (pair) {
        om[3] = u0.y; om[4] = u1.y; om[5] = u2.y;
        f4a S2; S2.x = o00.y; S2.y = o01.y; S2.z = o02.y; S2.w = o01.y;
        f4a S3; S3.x = o11.y; S3.y = o12.y; S3.z = o02.y; S3.w = o12.y;
        ((f4a*)(oc + 9))[0] = S2; ((f4a*)(oc + 9))[1] = S3; oc[17] = o22.y;
    }
}

extern "C" void kernel_launch(void* const* d_in, const int* in_sizes, int n_in,
                              void* d_out, int out_size, void* d_ws, size_t ws_size,
                              hipStream_t stream) {
    const float* miu1 = (const float*)d_in[0];
    const float* miu2 = (const float*)d_in[1];
    const float* cov1 = (const float*)d_in[2];
    const float* cov2 = (const float*)d_in[3];
    float* out = (float*)d_out;
    int B  = in_sizes[0] / 3;
    int nT = (B + 1) / 2;
    int threads = 256;
    int blocks = (nT + threads - 1) / threads;
    hipLaunchKernelGGL(wasserstein_log_kernel, dim3(blocks), dim3(threads), 0, stream,
                       miu1, miu2, cov1, cov2, out, B);
}

// Round 6
// 99.614 us; speedup vs baseline: 1.0372x; 1.0372x over previous
//
#include <hip/hip_runtime.h>
#include <math.h>

#define EPS 1e-8f

// 4B-aligned vector types: HW supports dword-aligned dwordx4/x2 global ops
// (pattern validated for correctness in round 5; pair stride 72B is 8B-aligned).
typedef float f4a __attribute__((ext_vector_type(4), aligned(4)));
typedef float f2a __attribute__((ext_vector_type(2), aligned(4)));

// Jacobi angle for 2x2 block [[app,apq],[apq,aqq]]: 2 transcendentals (both rsq).
//   r = sqrt(h^2+4apq^2), cos2t = |h|/r, c = sqrt((1+cos2t)/2),
//   s = sign(h)*apq/(r*c), |t*apq| = (r-|h|)/2 (exact identity).
// |h|+1e-18 => rad >= 1e-36 (normal); h=apq=0 yields identity rotation.
static __device__ __forceinline__ void jangle(float app, float aqq, float apq,
                                              float &c, float &s, float &app2, float &aqq2) {
    float h     = aqq - app;
    float ah    = fabsf(h) + 1e-18f;
    float v     = apq + apq;
    float rad   = fmaf(ah, ah, v * v);
    float rr    = __builtin_amdgcn_rsqf(rad);
    float c2h   = fmaf(0.5f * ah, rr, 0.5f);      // cos^2(theta) in (0.5, 1]
    float rc2   = __builtin_amdgcn_rsqf(c2h);
    c = c2h * rc2;
    float apq_s = (h < 0.0f) ? -apq : apq;
    s = apq_s * (rr * rc2);
    float dl    = copysignf(0.5f * (rad * rr - ah), h);   // t*apq, signed
    app2 = app - dl;
    aqq2 = aqq + dl;
}

// 3-sweep cyclic Jacobi on symmetric (a00..a22); Q = eigenvectors, diag -> eigvals.
// Sweep 1 specialized for Q == identity.
static __device__ __forceinline__ void eigh3(
    float &a00, float &a01, float &a02, float &a11, float &a12, float &a22,
    float &q00, float &q01, float &q02,
    float &q10, float &q11, float &q12,
    float &q20, float &q21, float &q22)
{
    float c, s, x, y, t0, t1;
    // sweep 1 (Q specialized)
    jangle(a00, a11, a01, c, s, x, y); a00 = x; a11 = y; a01 = 0.0f;
    t0 = a02; t1 = a12; a02 = fmaf(c, t0, -s * t1); a12 = fmaf(c, t1, s * t0);
    q00 = c; q01 = s; q10 = -s; q11 = c;

    jangle(a00, a22, a02, c, s, x, y); a00 = x; a22 = y; a02 = 0.0f;
    t0 = a01; t1 = a12; a01 = fmaf(c, t0, -s * t1); a12 = fmaf(c, t1, s * t0);
    q02 = s * q00; q12 = s * q10; q20 = -s; q22 = c;
    q00 = c * q00; q10 = c * q10;

    jangle(a11, a22, a12, c, s, x, y); a11 = x; a22 = y; a12 = 0.0f;
    t0 = a01; t1 = a02; a01 = fmaf(c, t0, -s * t1); a02 = fmaf(c, t1, s * t0);
    t0 = q01; t1 = q02; q01 = fmaf(c, t0, -s * t1); q02 = fmaf(s, t0, c * t1);
    t0 = q11; t1 = q12; q11 = fmaf(c, t0, -s * t1); q12 = fmaf(s, t0, c * t1);
    q21 = -s * q22; q22 = c * q22;

    // sweeps 2..3 (generic)
    #pragma unroll
    for (int sw = 0; sw < 2; ++sw) {
        jangle(a00, a11, a01, c, s, x, y); a00 = x; a11 = y; a01 = 0.0f;
        t0 = a02; t1 = a12; a02 = fmaf(c, t0, -s * t1); a12 = fmaf(c, t1, s * t0);
        t0 = q00; t1 = q01; q00 = fmaf(c, t0, -s * t1); q01 = fmaf(s, t0, c * t1);
        t0 = q10; t1 = q11; q10 = fmaf(c, t0, -s * t1); q11 = fmaf(s, t0, c * t1);
        t0 = q20; t1 = q21; q20 = fmaf(c, t0, -s * t1); q21 = fmaf(s, t0, c * t1);

        jangle(a00, a22, a02, c, s, x, y); a00 = x; a22 = y; a02 = 0.0f;
        t0 = a01; t1 = a12; a01 = fmaf(c, t0, -s * t1); a12 = fmaf(c, t1, s * t0);
        t0 = q00; t1 = q02; q00 = fmaf(c, t0, -s * t1); q02 = fmaf(s, t0, c * t1);
        t0 = q10; t1 = q12; q10 = fmaf(c, t0, -s * t1); q12 = fmaf(s, t0, c * t1);
        t0 = q20; t1 = q22; q20 = fmaf(c, t0, -s * t1); q22 = fmaf(s, t0, c * t1);

        jangle(a11, a22, a12, c, s, x, y); a11 = x; a22 = y; a12 = 0.0f;
        t0 = a01; t1 = a02; a01 = fmaf(c, t0, -s * t1); a02 = fmaf(c, t1, s * t0);
        t0 = q01; t1 = q02; q01 = fmaf(c, t0, -s * t1); q02 = fmaf(s, t0, c * t1);
        t0 = q11; t1 = q12; q11 = fmaf(c, t0, -s * t1); q12 = fmaf(s, t0, c * t1);
        t0 = q21; t1 = q22; q21 = fmaf(c, t0, -s * t1); q22 = fmaf(s, t0, c * t1);
    }
}

// Full per-element pipeline (R4 math, verbatim): inputs k=cov1, m=cov2 (symmetric
// 6-scalar form); outputs o = cov_velocity (symmetric 6-scalar form).
static __device__ __forceinline__ void wlog_elem(
    float k00, float k01, float k02, float k11, float k12, float k22,
    float m00, float m01, float m02, float m11, float m12, float m22,
    float &o00, float &o01, float &o02, float &o11, float &o12, float &o22)
{
    float a00 = k00 + EPS, a01 = k01, a02 = k02,
          a11 = k11 + EPS, a12 = k12, a22 = k22 + EPS;
    float q00, q01, q02, q10, q11, q12, q20, q21, q22;
    eigh3(a00, a01, a02, a11, a12, a22,
          q00, q01, q02, q10, q11, q12, q20, q21, q22);

    float w0 = fmaxf(fabsf(a00), 1e-12f);
    float w1 = fmaxf(fabsf(a11), 1e-12f);
    float w2 = fmaxf(fabsf(a22), 1e-12f);
    float di0 = __builtin_amdgcn_rsqf(w0), di1 = __builtin_amdgcn_rsqf(w1),
          di2 = __builtin_amdgcn_rsqf(w2);
    float d0 = w0 * di0, d1 = w1 * di1, d2 = w2 * di2;   // sqrt(w)

    // T = M Q ; G = Q^T T (symmetric)
    float T00 = fmaf(m00, q00, fmaf(m01, q10, m02 * q20));
    float T01 = fmaf(m00, q01, fmaf(m01, q11, m02 * q21));
    float T02 = fmaf(m00, q02, fmaf(m01, q12, m02 * q22));
    float T10 = fmaf(m01, q00, fmaf(m11, q10, m12 * q20));
    float T11 = fmaf(m01, q01, fmaf(m11, q11, m12 * q21));
    float T12 = fmaf(m01, q02, fmaf(m11, q12, m12 * q22));
    float T20 = fmaf(m02, q00, fmaf(m12, q10, m22 * q20));
    float T21 = fmaf(m02, q01, fmaf(m12, q11, m22 * q21));
    float T22 = fmaf(m02, q02, fmaf(m12, q12, m22 * q22));

    float g00 = fmaf(q00, T00, fmaf(q10, T10, q20 * T20));
    float g01 = fmaf(q00, T01, fmaf(q10, T11, q20 * T21));
    float g02 = fmaf(q00, T02, fmaf(q10, T12, q20 * T22));
    float g11 = fmaf(q01, T01, fmaf(q11, T11, q21 * T21));
    float g12 = fmaf(q01, T02, fmaf(q11, T12, q21 * T22));
    float g22 = fmaf(q02, T02, fmaf(q12, T12, q22 * T22));

    // C' = D G D + eps I
    float cp00 = fmaf(w0, g00, EPS);
    float cp11 = fmaf(w1, g11, EPS);
    float cp22 = fmaf(w2, g22, EPS);
    float cp01 = d0 * d1 * g01;
    float cp02 = d0 * d2 * g02;
    float cp12 = d1 * d2 * g12;

    // eigh(C')
    float e00, e01, e02, e10, e11, e12, e20, e21, e22;
    eigh3(cp00, cp01, cp02, cp11, cp12, cp22,
          e00, e01, e02, e10, e11, e12, e20, e21, e22);
    float u0 = fmaxf(fabsf(cp00), 1e-12f);
    float u1 = fmaxf(fabsf(cp11), 1e-12f);
    float u2 = fmaxf(fabsf(cp22), 1e-12f);
    float ts0 = u0 * __builtin_amdgcn_rsqf(u0);
    float ts1 = u1 * __builtin_amdgcn_rsqf(u1);
    float ts2 = u2 * __builtin_amdgcn_rsqf(u2);

    // U = Q D Qc, P = Q D^-1 Qc
    float Ed00 = d0*e00, Ed01 = d0*e01, Ed02 = d0*e02;
    float Ed10 = d1*e10, Ed11 = d1*e11, Ed12 = d1*e12;
    float Ed20 = d2*e20, Ed21 = d2*e21, Ed22 = d2*e22;
    float Ei00 = di0*e00, Ei01 = di0*e01, Ei02 = di0*e02;
    float Ei10 = di1*e10, Ei11 = di1*e11, Ei12 = di1*e12;
    float Ei20 = di2*e20, Ei21 = di2*e21, Ei22 = di2*e22;

    float U00 = fmaf(q00, Ed00, fmaf(q01, Ed10, q02 * Ed20));
    float U01 = fmaf(q00, Ed01, fmaf(q01, Ed11, q02 * Ed21));
    float U02 = fmaf(q00, Ed02, fmaf(q01, Ed12, q02 * Ed22));
    float U10 = fmaf(q10, Ed00, fmaf(q11, Ed10, q12 * Ed20));
    float U11 = fmaf(q10, Ed01, fmaf(q11, Ed11, q12 * Ed21));
    float U12 = fmaf(q10, Ed02, fmaf(q11, Ed12, q12 * Ed22));
    float U20 = fmaf(q20, Ed00, fmaf(q21, Ed10, q22 * Ed20));
    float U21 = fmaf(q20, Ed01, fmaf(q21, Ed11, q22 * Ed21));
    float U22 = fmaf(q20, Ed02, fmaf(q21, Ed12, q22 * Ed22));

    float P00 = fmaf(q00, Ei00, fmaf(q01, Ei10, q02 * Ei20));
    float P01 = fmaf(q00, Ei01, fmaf(q01, Ei11, q02 * Ei21));
    float P02 = fmaf(q00, Ei02, fmaf(q01, Ei12, q02 * Ei22));
    float P10 = fmaf(q10, Ei00, fmaf(q11, Ei10, q12 * Ei20));
    float P11 = fmaf(q10, Ei01, fmaf(q11, Ei11, q12 * Ei21));
    float P12 = fmaf(q10, Ei02, fmaf(q11, Ei12, q12 * Ei22));
    float P20 = fmaf(q20, Ei00, fmaf(q21, Ei10, q22 * Ei20));
    float P21 = fmaf(q20, Ei01, fmaf(q21, Ei11, q22 * Ei21));
    float P22 = fmaf(q20, Ei02, fmaf(q21, Ei12, q22 * Ei22));

    // W = U diag(ts) P^T + P diag(ts) U^T (symmetric)
    float A0 = ts0 * U00, A1 = ts1 * U01, A2 = ts2 * U02;
    float B0 = ts0 * U10, B1 = ts1 * U11, B2 = ts2 * U12;
    float C0 = ts0 * U20, C1 = ts1 * U21, C2 = ts2 * U22;

    float W00 = 2.0f * fmaf(A0, P00, fmaf(A1, P01, A2 * P02));
    float W11 = 2.0f * fmaf(B0, P10, fmaf(B1, P11, B2 * P12));
    float W22 = 2.0f * fmaf(C0, P20, fmaf(C1, P21, C2 * P22));
    float W01 = fmaf(A0, P10, fmaf(A1, P11, fmaf(A2, P12,
                fmaf(B0, P00, fmaf(B1, P01, B2 * P02)))));
    float W02 = fmaf(A0, P20, fmaf(A1, P21, fmaf(A2, P22,
                fmaf(C0, P00, fmaf(C1, P01, C2 * P02)))));
    float W12 = fmaf(B0, P20, fmaf(B1, P21, fmaf(B2, P22,
                fmaf(C0, P10, fmaf(C1, P11, C2 * P12)))));

    o00 = fmaf(-2.0f, k00, W00);
    o01 = fmaf(-2.0f, k01, W01);
    o02 = fmaf(-2.0f, k02, W02);
    o11 = fmaf(-2.0f, k11, W11);
    o12 = fmaf(-2.0f, k12, W12);
    o22 = fmaf(-2.0f, k22, W22);
}

__global__ __launch_bounds__(256) void wasserstein_log_kernel(
    const float* __restrict__ miu1, const float* __restrict__ miu2,
    const float* __restrict__ cov1, const float* __restrict__ cov2,
    float* __restrict__ out, int B)
{
    int b0 = blockIdx.x * blockDim.x + threadIdx.x;
    int nT = (B + 1) >> 1;
    if (b0 >= nT) return;

    if (2 * b0 + 1 < B) {
        // ---- pair path: elements 2b0, 2b0+1 — wide loads up-front ----
        size_t cb = 18 * (size_t)b0;
        const f4a* p1 = (const f4a*)(cov1 + cb);
        f4a Pa0 = p1[0], Pa1 = p1[1], Pa2 = p1[2], Pa3 = p1[3];
        f2a Pa4 = *(const f2a*)(cov1 + cb + 16);
        const f4a* p2 = (const f4a*)(cov2 + cb);
        f4a Pb0 = p2[0], Pb1 = p2[1], Pb2 = p2[2], Pb3 = p2[3];
        f2a Pb4 = *(const f2a*)(cov2 + cb + 16);

        size_t mb = 6 * (size_t)b0;
        f4a M10 = *(const f4a*)(miu1 + mb);
        f2a M11 = *(const f2a*)(miu1 + mb + 4);
        f4a M20 = *(const f4a*)(miu2 + mb);
        f2a M21 = *(const f2a*)(miu2 + mb + 4);

        // miu diff, both elements, coalesced store
        f4a UM; UM.x = M20.x - M10.x; UM.y = M20.y - M10.y;
                UM.z = M20.z - M10.z; UM.w = M20.w - M10.w;
        f2a UM2; UM2.x = M21.x - M11.x; UM2.y = M21.y - M11.y;
        *(f4a*)(out + mb) = UM;
        *(f2a*)(out + mb + 4) = UM2;

        // element A: dwords 0..8 -> sym entries 0,1,2,4,5,8
        float oA00, oA01, oA02, oA11, oA12, oA22;
        wlog_elem(Pa0.x, Pa0.y, Pa0.z, Pa1.x, Pa1.y, Pa2.x,
                  Pb0.x, Pb0.y, Pb0.z, Pb1.x, Pb1.y, Pb2.x,
                  oA00, oA01, oA02, oA11, oA12, oA22);
        // element B: dwords 9..17 -> sym entries 9,10,11,13,14,17
        float oB00, oB01, oB02, oB11, oB12, oB22;
        wlog_elem(Pa2.y, Pa2.z, Pa2.w, Pa3.y, Pa3.z, Pa4.y,
                  Pb2.y, Pb2.z, Pb2.w, Pb3.y, Pb3.z, Pb4.y,
                  oB00, oB01, oB02, oB11, oB12, oB22);

        // cov_velocity stores: 18 contiguous dwords, fully vectorized
        float* oc = out + 3 * (size_t)B + cb;
        f4a S0; S0.x = oA00; S0.y = oA01; S0.z = oA02; S0.w = oA01;
        f4a S1; S1.x = oA11; S1.y = oA12; S1.z = oA02; S1.w = oA12;
        f4a S2; S2.x = oA22; S2.y = oB00; S2.z = oB01; S2.w = oB02;
        f4a S3; S3.x = oB01; S3.y = oB11; S3.z = oB12; S3.w = oB02;
        f2a S4; S4.x = oB12; S4.y = oB22;
        ((f4a*)oc)[0] = S0; ((f4a*)oc)[1] = S1;
        ((f4a*)oc)[2] = S2; ((f4a*)oc)[3] = S3;
        *(f2a*)(oc + 16) = S4;
    } else {
        // ---- tail (odd B only): single element B-1, scalar path ----
        int b = B - 1;
        size_t cb = 9 * (size_t)b;
        float k00 = cov1[cb+0], k01 = cov1[cb+1], k02 = cov1[cb+2],
              k11 = cov1[cb+4], k12 = cov1[cb+5], k22 = cov1[cb+8];
        float m00 = cov2[cb+0], m01 = cov2[cb+1], m02 = cov2[cb+2],
              m11 = cov2[cb+4], m12 = cov2[cb+5], m22 = cov2[cb+8];
        size_t mbs = 3 * (size_t)b;
        out[mbs+0] = miu2[mbs+0] - miu1[mbs+0];
        out[mbs+1] = miu2[mbs+1] - miu1[mbs+1];
        out[mbs+2] = miu2[mbs+2] - miu1[mbs+2];
        float o00, o01, o02, o11, o12, o22;
        wlog_elem(k00, k01, k02, k11, k12, k22,
                  m00, m01, m02, m11, m12, m22,
                  o00, o01, o02, o11, o12, o22);
        float* oc = out + 3 * (size_t)B + cb;
        oc[0] = o00; oc[1] = o01; oc[2] = o02;
        oc[3] = o01; oc[4] = o11; oc[5] = o12;
        oc[6] = o02; oc[7] = o12; oc[8] = o22;
    }
}

extern "C" void kernel_launch(void* const* d_in, const int* in_sizes, int n_in,
                              void* d_out, int out_size, void* d_ws, size_t ws_size,
                              hipStream_t stream) {
    const float* miu1 = (const float*)d_in[0];
    const float* miu2 = (const float*)d_in[1];
    const float* cov1 = (const float*)d_in[2];
    const float* cov2 = (const float*)d_in[3];
    float* out = (float*)d_out;
    int B  = in_sizes[0] / 3;
    int nT = (B + 1) / 2;
    int threads = 256;
    int blocks = (nT + threads - 1) / threads;
    hipLaunchKernelGGL(wasserstein_log_kernel, dim3(blocks), dim3(threads), 0, stream,
                       miu1, miu2, cov1, cov2, out, B);
}

// Round 7
// 99.189 us; speedup vs baseline: 1.0416x; 1.0043x over previous
//
#include <hip/hip_runtime.h>
#include <math.h>

#define EPS 1e-8f

typedef float f4a __attribute__((ext_vector_type(4), aligned(4)));
typedef float f2a __attribute__((ext_vector_type(2), aligned(4)));

// Closed-form cov_velocity via Cayley-Hamilton square root of P = cov1*cov2.
//   X = P^{1/2} = (t*P + d*I) (P + m*I)^{-1},  d = sqrt(det P),
//   t = tr X solves t^4 - 2*I1*t^2 - 8*d*t + (I1^2 - 4*I2) = 0 (largest root),
//   m = (t^2 - I1)/2.
// cov_velocity = X + X^T - 2*cov1. Identical to the reference's
// eigh-based pipeline up to O(1e-8) EPS perturbations (absorbed: X is the
// unique principal sqrt; V_ref^2 = cov1*cov2 exactly).
static __device__ __forceinline__ void wlog_elem(
    float k00, float k01, float k02, float k11, float k12, float k22,
    float m00, float m01, float m02, float m11, float m12, float m22,
    float &o00, float &o01, float &o02, float &o11, float &o12, float &o22)
{
    // cov1 + EPS*I (match reference's A_sqrt argument)
    float e00 = k00 + EPS, e11 = k11 + EPS, e22 = k22 + EPS;

    // ---- P = (cov1+eps I) * cov2 (both symmetric; P general) ----
    float P00 = fmaf(e00, m00, fmaf(k01, m01, k02 * m02));
    float P01 = fmaf(e00, m01, fmaf(k01, m11, k02 * m12));
    float P02 = fmaf(e00, m02, fmaf(k01, m12, k02 * m22));
    float P10 = fmaf(k01, m00, fmaf(e11, m01, k12 * m02));
    float P11 = fmaf(k01, m01, fmaf(e11, m11, k12 * m12));
    float P12 = fmaf(k01, m02, fmaf(e11, m12, k12 * m22));
    float P20 = fmaf(k02, m00, fmaf(k12, m01, e22 * m02));
    float P21 = fmaf(k02, m01, fmaf(k12, m11, e22 * m12));
    float P22 = fmaf(k02, m02, fmaf(k12, m12, e22 * m22));

    // ---- invariants ----
    float I1 = P00 + P11 + P22;
    float I2 = fmaf(P00, P11, -P01 * P10)
             + fmaf(P00, P22, -P02 * P20)
             + fmaf(P11, P22, -P12 * P21);
    // det(cov1+epsI) * det(cov2): more stable than det(P) directly
    float dK = fmaf(e00, fmaf(e11, e22, -k12 * k12),
               fmaf(-k01, fmaf(k01, e22, -k12 * k02),
                     k02 * fmaf(k01, k12, -e11 * k02)));
    float dM = fmaf(m00, fmaf(m11, m22, -m12 * m12),
               fmaf(-m01, fmaf(m01, m22, -m12 * m02),
                     m02 * fmaf(m01, m12, -m11 * m02)));
    float I3 = fmaxf(dK * dM, 1e-30f);
    float d  = sqrtf(I3);

    // ---- t = largest root of t^4 - 2I1 t^2 - 8dt + (I1^2-4I2) ----
    // Upper seed: t* <= sqrt(3*I1); m <= m_up = sqrt(I2 + 2*sqrt(3I1)*d);
    // t0 = sqrt(I1 + 2*m_up) >= t*. f convex for t >= sqrt(I1/3)*... ->
    // Newton from above is monotone decreasing, quadratic.
    float I1p  = fmaxf(I1, 1e-30f);
    float m_up = sqrtf(fmaxf(fmaf(2.0f * sqrtf(3.0f * I1p), d, I2), 0.0f));
    float t    = sqrtf(fmaf(2.0f, m_up, I1p));
    float K2   = fmaf(I1, I1, -4.0f * I2);
    float I1_2 = I1 + I1;
    float I1_4 = I1_2 + I1_2;
    float d8   = 8.0f * d;
    #pragma unroll
    for (int it = 0; it < 5; ++it) {
        float t2 = t * t;
        float f  = fmaf(t2, t2 - I1_2, fmaf(-d8, t, K2));
        float fp = fmaf(t, fmaf(4.0f, t2, -I1_4), -d8);
        t = fmaf(-f, __builtin_amdgcn_rcpf(fp), t);
    }
    float m = 0.5f * fmaf(t, t, -I1);

    // ---- N = P + m*I ; cofactor matrix & det ----
    float N00 = P00 + m, N11 = P11 + m, N22 = P22 + m;
    float C00 = fmaf(N11, N22, -P12 * P21);
    float C01 = fmaf(P12, P20, -P10 * N22);
    float C02 = fmaf(P10, P21, -N11 * P20);
    float C10 = fmaf(P02, P21, -P01 * N22);
    float C11 = fmaf(N00, N22, -P02 * P20);
    float C12 = fmaf(P01, P20, -N00 * P21);
    float C20 = fmaf(P01, P12, -P02 * N11);
    float C21 = fmaf(P02, P10, -N00 * P12);
    float C22 = fmaf(N00, N11, -P01 * P10);
    float det = fmaf(N00, C00, fmaf(P01, C01, P02 * C02));
    float rdet = __builtin_amdgcn_rcpf(det);

    // ---- Y = t*P + d*I ; Z = Y * adj(N)  (X = rdet * Z) ----
    float Y00 = fmaf(t, P00, d), Y01 = t * P01, Y02 = t * P02;
    float Y10 = t * P10, Y11 = fmaf(t, P11, d), Y12 = t * P12;
    float Y20 = t * P20, Y21 = t * P21, Y22 = fmaf(t, P22, d);

    float Z00 = fmaf(Y00, C00, fmaf(Y01, C01, Y02 * C02));
    float Z01 = fmaf(Y00, C10, fmaf(Y01, C11, Y02 * C12));
    float Z02 = fmaf(Y00, C20, fmaf(Y01, C21, Y02 * C22));
    float Z10 = fmaf(Y10, C00, fmaf(Y11, C01, Y12 * C02));
    float Z11 = fmaf(Y10, C10, fmaf(Y11, C11, Y12 * C12));
    float Z12 = fmaf(Y10, C20, fmaf(Y11, C21, Y12 * C22));
    float Z20 = fmaf(Y20, C00, fmaf(Y21, C01, Y22 * C02));
    float Z21 = fmaf(Y20, C10, fmaf(Y21, C11, Y22 * C12));
    float Z22 = fmaf(Y20, C20, fmaf(Y21, C21, Y22 * C22));

    // ---- cov_velocity = rdet*(Z + Z^T) - 2*cov1 ----
    o00 = fmaf(rdet, Z00 + Z00, -2.0f * k00);
    o01 = fmaf(rdet, Z01 + Z10, -2.0f * k01);
    o02 = fmaf(rdet, Z02 + Z20, -2.0f * k02);
    o11 = fmaf(rdet, Z11 + Z11, -2.0f * k11);
    o12 = fmaf(rdet, Z12 + Z21, -2.0f * k12);
    o22 = fmaf(rdet, Z22 + Z22, -2.0f * k22);
}

__global__ __launch_bounds__(256) void wasserstein_log_kernel(
    const float* __restrict__ miu1, const float* __restrict__ miu2,
    const float* __restrict__ cov1, const float* __restrict__ cov2,
    float* __restrict__ out, int B)
{
    int b0 = blockIdx.x * blockDim.x + threadIdx.x;
    int nT = (B + 1) >> 1;
    if (b0 >= nT) return;

    if (2 * b0 + 1 < B) {
        // ---- pair path: elements 2b0, 2b0+1 — wide loads up-front ----
        size_t cb = 18 * (size_t)b0;
        const f4a* p1 = (const f4a*)(cov1 + cb);
        f4a Pa0 = p1[0], Pa1 = p1[1], Pa2 = p1[2], Pa3 = p1[3];
        f2a Pa4 = *(const f2a*)(cov1 + cb + 16);
        const f4a* p2 = (const f4a*)(cov2 + cb);
        f4a Pb0 = p2[0], Pb1 = p2[1], Pb2 = p2[2], Pb3 = p2[3];
        f2a Pb4 = *(const f2a*)(cov2 + cb + 16);

        size_t mb = 6 * (size_t)b0;
        f4a M10 = *(const f4a*)(miu1 + mb);
        f2a M11 = *(const f2a*)(miu1 + mb + 4);
        f4a M20 = *(const f4a*)(miu2 + mb);
        f2a M21 = *(const f2a*)(miu2 + mb + 4);

        f4a UM; UM.x = M20.x - M10.x; UM.y = M20.y - M10.y;
                UM.z = M20.z - M10.z; UM.w = M20.w - M10.w;
        f2a UM2; UM2.x = M21.x - M11.x; UM2.y = M21.y - M11.y;
        *(f4a*)(out + mb) = UM;
        *(f2a*)(out + mb + 4) = UM2;

        float oA00, oA01, oA02, oA11, oA12, oA22;
        wlog_elem(Pa0.x, Pa0.y, Pa0.z, Pa1.x, Pa1.y, Pa2.x,
                  Pb0.x, Pb0.y, Pb0.z, Pb1.x, Pb1.y, Pb2.x,
                  oA00, oA01, oA02, oA11, oA12, oA22);
        float oB00, oB01, oB02, oB11, oB12, oB22;
        wlog_elem(Pa2.y, Pa2.z, Pa2.w, Pa3.y, Pa3.z, Pa4.y,
                  Pb2.y, Pb2.z, Pb2.w, Pb3.y, Pb3.z, Pb4.y,
                  oB00, oB01, oB02, oB11, oB12, oB22);

        float* oc = out + 3 * (size_t)B + cb;
        f4a S0; S0.x = oA00; S0.y = oA01; S0.z = oA02; S0.w = oA01;
        f4a S1; S1.x = oA11; S1.y = oA12; S1.z = oA02; S1.w = oA12;
        f4a S2; S2.x = oA22; S2.y = oB00; S2.z = oB01; S2.w = oB02;
        f4a S3; S3.x = oB01; S3.y = oB11; S3.z = oB12; S3.w = oB02;
        f2a S4; S4.x = oB12; S4.y = oB22;
        ((f4a*)oc)[0] = S0; ((f4a*)oc)[1] = S1;
        ((f4a*)oc)[2] = S2; ((f4a*)oc)[3] = S3;
        *(f2a*)(oc + 16) = S4;
    } else {
        // ---- tail (odd B only) ----
        int b = B - 1;
        size_t cb = 9 * (size_t)b;
        float k00 = cov1[cb+0], k01 = cov1[cb+1], k02 = cov1[cb+2],
              k11 = cov1[cb+4], k12 = cov1[cb+5], k22 = cov1[cb+8];
        float m00 = cov2[cb+0], m01 = cov2[cb+1], m02 = cov2[cb+2],
              m11 = cov2[cb+4], m12 = cov2[cb+5], m22 = cov2[cb+8];
        size_t mbs = 3 * (size_t)b;
        out[mbs+0] = miu2[mbs+0] - miu1[mbs+0];
        out[mbs+1] = miu2[mbs+1] - miu1[mbs+1];
        out[mbs+2] = miu2[mbs+2] - miu1[mbs+2];
        float o00, o01, o02, o11, o12, o22;
        wlog_elem(k00, k01, k02, k11, k12, k22,
                  m00, m01, m02, m11, m12, m22,
                  o00, o01, o02, o11, o12, o22);
        float* oc = out + 3 * (size_t)B + cb;
        oc[0] = o00; oc[1] = o01; oc[2] = o02;
        oc[3] = o01; oc[4] = o11; oc[5] = o12;
        oc[6] = o02; oc[7] = o12; oc[8] = o22;
    }
}

extern "C" void kernel_launch(void* const* d_in, const int* in_sizes, int n_in,
                              void* d_out, int out_size, void* d_ws, size_t ws_size,
                              hipStream_t stream) {
    const float* miu1 = (const float*)d_in[0];
    const float* miu2 = (const float*)d_in[1];
    const float* cov1 = (const float*)d_in[2];
    const float* cov2 = (const float*)d_in[3];
    float* out = (float*)d_out;
    int B  = in_sizes[0] / 3;
    int nT = (B + 1) / 2;
    int threads = 256;
    int blocks = (nT + threads - 1) / threads;
    hipLaunchKernelGGL(wasserstein_log_kernel, dim3(blocks), dim3(threads), 0, stream,
                       miu1, miu2, cov1, cov2, out, B);
}